// Round 1
// baseline (262.318 us; speedup 1.0000x reference)
//
#include <hip/hip_runtime.h>

// Attention2d: B=2, C=128, H=W=64 (T=4096), NH=4 heads, ch=32.
// Pipeline (all matmuls via f16-input MFMA 16x16x32, fp32 accumulate):
//   k0: x fp32 [b][128][4096] -> Xh f16 [b][4096][128]  (LDS transpose)
//   k1: QKV GEMM (W 384x128 @ Xh^T) -> Qh [bh][t][32] (pre-scaled by
//       scale^2*log2e), Kh [bh][t][32], Vt [bh][32][t]
//   k2: flash attention per (bh, 64-q block): 64-key tiles in LDS,
//       online softmax in exp2 domain, DPP row-max, ones-column MFMA for l
//   k3: proj GEMM + bias + fp32 residual -> out fp32 [b][128][4096]

typedef _Float16 f16;
typedef _Float16 f16x8 __attribute__((ext_vector_type(8)));
typedef _Float16 f16x4 __attribute__((ext_vector_type(4)));
typedef float    f32x4 __attribute__((ext_vector_type(4)));

#define T_DIM 4096
#define C_DIM 128
#define CH    32
#define NH    4

// max within each 16-lane DPP row via row_ror butterflies (VALU-only,
// keeps the softmax reduction off the LDS pipe)
static __device__ __forceinline__ float rowmax16(float x) {
  int v;
  v = __builtin_amdgcn_update_dpp(__float_as_int(x), __float_as_int(x), 0x121, 0xF, 0xF, true);
  x = fmaxf(x, __int_as_float(v));
  v = __builtin_amdgcn_update_dpp(__float_as_int(x), __float_as_int(x), 0x122, 0xF, 0xF, true);
  x = fmaxf(x, __int_as_float(v));
  v = __builtin_amdgcn_update_dpp(__float_as_int(x), __float_as_int(x), 0x124, 0xF, 0xF, true);
  x = fmaxf(x, __int_as_float(v));
  v = __builtin_amdgcn_update_dpp(__float_as_int(x), __float_as_int(x), 0x128, 0xF, 0xF, true);
  x = fmaxf(x, __int_as_float(v));
  return x;
}

// ---------------- kernel 0: cast + transpose x ----------------
__global__ __launch_bounds__(256) void k_transpose_x(const float* __restrict__ x,
                                                     f16* __restrict__ xh) {
  // grid (T/64, B); block handles 64 t x 128 c
  __shared__ f16 tile[64][C_DIM + 8];   // stride 136 f16 = 272B (16B aligned)
  int tid = threadIdx.x;
  int t0  = blockIdx.x * 64;
  int b   = blockIdx.y;
  int tl  = tid & 63;        // t within tile (coalesced dim for reads)
  int cg  = tid >> 6;        // 4 c-groups of 32
  const float* xb = x + (size_t)b * C_DIM * T_DIM;
#pragma unroll 4
  for (int k = 0; k < 32; k += 2) {
    int c = cg * 32 + k;
    float v0 = xb[(size_t)c * T_DIM + t0 + tl];
    float v1 = xb[(size_t)(c + 1) * T_DIM + t0 + tl];
    union { f16 h[2]; unsigned u; } p;
    p.h[0] = (f16)v0; p.h[1] = (f16)v1;
    *(unsigned*)&tile[tl][c] = p.u;   // c even -> 4B aligned
  }
  __syncthreads();
  f16* xo = xh + ((size_t)b * T_DIM + t0) * C_DIM;
  int ch = tid & 15;
#pragma unroll
  for (int i = 0; i < 4; ++i) {
    int r = (tid >> 4) + i * 16;
    f16x8 v = *(const f16x8*)&tile[r][ch * 8];
    *(f16x8*)(xo + (size_t)r * C_DIM + ch * 8) = v;   // coalesced 16B stores
  }
}

// ---------------- kernel 1: QKV projection GEMM ----------------
__global__ __launch_bounds__(256) void k_qkv(const f16* __restrict__ xh,
                                             const float* __restrict__ wqkv,
                                             const float* __restrict__ bqkv,
                                             f16* __restrict__ qh,
                                             f16* __restrict__ kh,
                                             f16* __restrict__ vt) {
  // grid (6, 64, B); 4 waves; wave tile = 16 o x 64 t, K=128
  int tid = threadIdx.x;
  int w = tid >> 6, lane = tid & 63;
  int l15 = lane & 15, quad = lane >> 4;
  int o0 = blockIdx.x * 64 + w * 16;
  int t0 = blockIdx.y * 64;
  int b  = blockIdx.z;
  const f16* xb = xh + ((size_t)b * T_DIM + t0) * C_DIM;

  f32x4 acc[4] = {{0,0,0,0},{0,0,0,0},{0,0,0,0},{0,0,0,0}};
#pragma unroll
  for (int kc = 0; kc < 4; ++kc) {
    const float* wp = wqkv + (size_t)(o0 + l15) * C_DIM + kc * 32 + quad * 8;
    f16x8 af;
#pragma unroll
    for (int i = 0; i < 8; ++i) af[i] = (f16)wp[i];
#pragma unroll
    for (int nf = 0; nf < 4; ++nf) {
      f16x8 bf = *(const f16x8*)(xb + (size_t)(nf * 16 + l15) * C_DIM + kc * 32 + quad * 8);
      acc[nf] = __builtin_amdgcn_mfma_f32_16x16x32_f16(af, bf, acc[nf], 0, 0, 0);
    }
  }
  // epilogue: o = o0 + quad*4 + r (4-run never crosses a 32-group boundary)
  int ob   = o0 + quad * 4;
  int head = ob / 96;
  int r96  = ob % 96;
  int grp  = r96 >> 5;          // 0=Q 1=K 2=V
  int c0   = r96 & 31;
  int bh   = b * NH + head;
  float bias[4];
#pragma unroll
  for (int r = 0; r < 4; ++r) bias[r] = bqkv[ob + r];
  // scale^2 * log2(e): logits land pre-scaled for exp2-domain softmax
  const float SCALE2 = 0.17677669529663687f * 1.4426950408889634f;
#pragma unroll
  for (int nf = 0; nf < 4; ++nf) {
    int t = t0 + nf * 16 + l15;
    float v[4];
#pragma unroll
    for (int r = 0; r < 4; ++r) v[r] = acc[nf][r] + bias[r];
    if (grp == 0) {
      f16x4 q;
#pragma unroll
      for (int r = 0; r < 4; ++r) q[r] = (f16)(v[r] * SCALE2);
      *(f16x4*)(qh + ((size_t)bh * T_DIM + t) * CH + c0) = q;
    } else if (grp == 1) {
      f16x4 kk;
#pragma unroll
      for (int r = 0; r < 4; ++r) kk[r] = (f16)v[r];
      *(f16x4*)(kh + ((size_t)bh * T_DIM + t) * CH + c0) = kk;
    } else {
#pragma unroll
      for (int r = 0; r < 4; ++r)
        vt[((size_t)bh * CH + c0 + r) * T_DIM + t] = (f16)v[r];
    }
  }
}

// ---------------- kernel 2: flash attention ----------------
__global__ __launch_bounds__(128) void k_attn(const f16* __restrict__ qh,
                                              const f16* __restrict__ kh,
                                              const f16* __restrict__ vt,
                                              f16* __restrict__ ah) {
  // grid (64, 8): x = 64-query block, y = bh. 2 waves x 32 q each.
  __shared__ f16 Ks[64][40];      // [s][c], padded 32->40 (bank spread)
  __shared__ f16 Vs[32][72];      // [c][s], padded 64->72
  __shared__ f16 Ps[2][32][72];   // per-wave P round-trip buffer
  int tid = threadIdx.x;
  int w = tid >> 6, lane = tid & 63;
  int l15 = lane & 15, quad = lane >> 4;
  int bh = blockIdx.y;
  int q0 = blockIdx.x * 64 + w * 32;

  // Q A-fragments (A[m=lane&15][k=quad*8+j])
  f16x8 qf[2];
#pragma unroll
  for (int qs = 0; qs < 2; ++qs)
    qf[qs] = *(const f16x8*)(qh + ((size_t)bh * T_DIM + q0 + qs * 16 + l15) * CH + quad * 8);

  f32x4 acc[2][2] = {{{0,0,0,0},{0,0,0,0}},{{0,0,0,0},{0,0,0,0}}};
  f32x4 accl[2]   = {{0,0,0,0},{0,0,0,0}};   // softmax denominator (col 0)
  float mrow[2][4];
#pragma unroll
  for (int qs = 0; qs < 2; ++qs)
#pragma unroll
    for (int r = 0; r < 4; ++r) mrow[qs][r] = -1e30f;

  f16x8 onesb;   // B-operand ones column: B[k][0]=1
#pragma unroll
  for (int i = 0; i < 8; ++i) onesb[i] = (l15 == 0) ? (f16)1.0f : (f16)0.0f;

  int ks_row = tid >> 1, ks_half  = tid & 1;
  int vs_row = tid >> 2, vs_chunk = tid & 3;
  const f32x4 zf = {0,0,0,0};

  for (int s0 = 0; s0 < T_DIM; s0 += 64) {
    __syncthreads();   // previous tile's LDS reads done before restage
    {
      const uint4* src = (const uint4*)(kh + ((size_t)bh * T_DIM + s0 + ks_row) * CH + ks_half * 16);
      uint4* dst = (uint4*)&Ks[ks_row][ks_half * 16];
      dst[0] = src[0]; dst[1] = src[1];
      const uint4* vsrc = (const uint4*)(vt + ((size_t)bh * CH + vs_row) * T_DIM + s0 + vs_chunk * 16);
      uint4* vdst = (uint4*)&Vs[vs_row][vs_chunk * 16];
      vdst[0] = vsrc[0]; vdst[1] = vsrc[1];
    }
    __syncthreads();

    // QK^T: S[q][s], 2 q-subtiles x 4 key-subtiles
    f16x8 kf[4];
#pragma unroll
    for (int nf = 0; nf < 4; ++nf)
      kf[nf] = *(const f16x8*)&Ks[nf * 16 + l15][quad * 8];
    f32x4 sf[2][4];
#pragma unroll
    for (int qs = 0; qs < 2; ++qs)
#pragma unroll
      for (int nf = 0; nf < 4; ++nf)
        sf[qs][nf] = __builtin_amdgcn_mfma_f32_16x16x32_f16(qf[qs], kf[nf], zf, 0, 0, 0);

    // online softmax (exp2 domain; logits already carry log2e)
#pragma unroll
    for (int qs = 0; qs < 2; ++qs) {
#pragma unroll
      for (int r = 0; r < 4; ++r) {
        float mx = fmaxf(fmaxf(sf[qs][0][r], sf[qs][1][r]),
                         fmaxf(sf[qs][2][r], sf[qs][3][r]));
        mx = rowmax16(mx);
        float mnew  = fmaxf(mrow[qs][r], mx);
        float alpha = exp2f(mrow[qs][r] - mnew);
        mrow[qs][r] = mnew;
        acc[qs][0][r] *= alpha;
        acc[qs][1][r] *= alpha;
        accl[qs][r]   *= alpha;
#pragma unroll
        for (int nf = 0; nf < 4; ++nf) {
          float p = exp2f(sf[qs][nf][r] - mnew);
          Ps[w][qs * 16 + quad * 4 + r][nf * 16 + l15] = (f16)p;  // C-layout out
        }
      }
    }

    // V B-fragments (B[k=s][n=c] from Vs[c][s])
    f16x8 vf[2][2];
#pragma unroll
    for (int kc = 0; kc < 2; ++kc)
#pragma unroll
      for (int ch = 0; ch < 2; ++ch)
        vf[kc][ch] = *(const f16x8*)&Vs[ch * 16 + l15][kc * 32 + quad * 8];

    // PV (+ ones column accumulates l); P read back in A-layout
#pragma unroll
    for (int qs = 0; qs < 2; ++qs) {
#pragma unroll
      for (int kc = 0; kc < 2; ++kc) {
        f16x8 pf = *(const f16x8*)&Ps[w][qs * 16 + l15][kc * 32 + quad * 8];
        acc[qs][0] = __builtin_amdgcn_mfma_f32_16x16x32_f16(pf, vf[kc][0], acc[qs][0], 0, 0, 0);
        acc[qs][1] = __builtin_amdgcn_mfma_f32_16x16x32_f16(pf, vf[kc][1], acc[qs][1], 0, 0, 0);
        accl[qs]   = __builtin_amdgcn_mfma_f32_16x16x32_f16(pf, onesb,     accl[qs],   0, 0, 0);
      }
    }
  }

  // epilogue: normalize by l (lives in col 0 of accl) and store f16
  int b = bh >> 2, head = bh & 3;
#pragma unroll
  for (int qs = 0; qs < 2; ++qs) {
#pragma unroll
    for (int r = 0; r < 4; ++r) {
      float l   = __shfl(accl[qs][r], (lane & 48));  // lane quad*16 holds col 0
      float inv = 1.0f / l;
      int t = q0 + qs * 16 + quad * 4 + r;
      size_t base = ((size_t)b * T_DIM + t) * C_DIM + head * 32;
      ah[base + l15]      = (f16)(acc[qs][0][r] * inv);
      ah[base + 16 + l15] = (f16)(acc[qs][1][r] * inv);
    }
  }
}

// ---------------- kernel 3: output projection + residual ----------------
__global__ __launch_bounds__(256) void k_proj(const f16* __restrict__ ah,
                                              const float* __restrict__ wp,
                                              const float* __restrict__ bp,
                                              const float* __restrict__ x,
                                              float* __restrict__ out) {
  // grid (2, 128, B); 4 waves; wave tile = 16 o x 32 t, K=128
  int tid = threadIdx.x;
  int w = tid >> 6, lane = tid & 63;
  int l15 = lane & 15, quad = lane >> 4;
  int o0 = blockIdx.x * 64 + w * 16;
  int t0 = blockIdx.y * 32;
  int b  = blockIdx.z;

  f32x4 acc[2] = {{0,0,0,0},{0,0,0,0}};
#pragma unroll
  for (int kc = 0; kc < 4; ++kc) {
    const float* wr = wp + (size_t)(o0 + l15) * C_DIM + kc * 32 + quad * 8;
    f16x8 af;
#pragma unroll
    for (int i = 0; i < 8; ++i) af[i] = (f16)wr[i];
#pragma unroll
    for (int nf = 0; nf < 2; ++nf) {
      f16x8 bf = *(const f16x8*)(ah + ((size_t)b * T_DIM + t0 + nf * 16 + l15) * C_DIM + kc * 32 + quad * 8);
      acc[nf] = __builtin_amdgcn_mfma_f32_16x16x32_f16(af, bf, acc[nf], 0, 0, 0);
    }
  }
  int ob = o0 + quad * 4;
  float bias[4];
#pragma unroll
  for (int r = 0; r < 4; ++r) bias[r] = bp[ob + r];
#pragma unroll
  for (int nf = 0; nf < 2; ++nf) {
#pragma unroll
    for (int r = 0; r < 4; ++r) {
      int t = t0 + nf * 16 + l15;
      size_t idx = ((size_t)b * C_DIM + ob + r) * T_DIM + t;
      out[idx] = x[idx] + bias[r] + acc[nf][r];
    }
  }
}

extern "C" void kernel_launch(void* const* d_in, const int* in_sizes, int n_in,
                              void* d_out, int out_size, void* d_ws, size_t ws_size,
                              hipStream_t stream) {
  const float* x     = (const float*)d_in[0];
  const float* wqkv  = (const float*)d_in[1];
  const float* bqkv  = (const float*)d_in[2];
  const float* wproj = (const float*)d_in[3];
  const float* bproj = (const float*)d_in[4];
  float* out = (float*)d_out;

  char* ws = (char*)d_ws;
  f16* Xh = (f16*)(ws);                       // 2MB; dead after k1, reused as Ah
  f16* Qh = (f16*)(ws + (2u << 20));          // 2MB
  f16* Kh = (f16*)(ws + (4u << 20));          // 2MB
  f16* Vt = (f16*)(ws + (6u << 20));          // 2MB
  f16* Ah = Xh;                               // alias: k1 reads finish before k2 writes

  k_transpose_x<<<dim3(64, 2), 256, 0, stream>>>(x, Xh);
  k_qkv<<<dim3(6, 64, 2), 256, 0, stream>>>(Xh, wqkv, bqkv, Qh, Kh, Vt);
  k_attn<<<dim3(64, 8), 128, 0, stream>>>(Qh, Kh, Vt, Ah);
  k_proj<<<dim3(2, 128, 2), 256, 0, stream>>>(Ah, wproj, bproj, x, out);
}

// Round 2
// 145.196 us; speedup vs baseline: 1.8066x; 1.8066x over previous
//
#include <hip/hip_runtime.h>

// Attention2d: B=2, C=128, H=W=64 (T=4096), NH=4 heads, ch=32.
//   k0: x fp32 [b][128][4096] -> Xh f16 [b][4096][128]  (LDS transpose)
//   k1: QKV GEMM -> Qh [bh][t][32] (pre-scaled by scale^2*log2e),
//       Kh [bh][t][32], Vt [bh][32][t]
//   k2: flash attention, SPLITS=4 key-partitions (flash-decoding style):
//       S^T via swapped MFMA (per-lane softmax), out^T = V^T P^T,
//       fp32 partials (acc, m, l) -> workspace
//   k2b: combine partials -> Ah f16 [b][t][128]
//   k3: proj GEMM + bias + fp32 residual

typedef _Float16 f16;
typedef _Float16 f16x8 __attribute__((ext_vector_type(8)));
typedef _Float16 f16x4 __attribute__((ext_vector_type(4)));
typedef float    f32x4 __attribute__((ext_vector_type(4)));

#define T_DIM 4096
#define C_DIM 128
#define CH    32
#define NH    4
#define NBH   8
#define SPLITS 4
#define S_SPLIT (T_DIM / SPLITS)
#define NTILES  (S_SPLIT / 64)

// ---------------- kernel 0: cast + transpose x ----------------
__global__ __launch_bounds__(256) void k_transpose_x(const float* __restrict__ x,
                                                     f16* __restrict__ xh) {
  __shared__ f16 tile[64][C_DIM + 8];
  int tid = threadIdx.x;
  int t0  = blockIdx.x * 64;
  int b   = blockIdx.y;
  int tl  = tid & 63;
  int cg  = tid >> 6;
  const float* xb = x + (size_t)b * C_DIM * T_DIM;
#pragma unroll 4
  for (int k = 0; k < 32; k += 2) {
    int c = cg * 32 + k;
    float v0 = xb[(size_t)c * T_DIM + t0 + tl];
    float v1 = xb[(size_t)(c + 1) * T_DIM + t0 + tl];
    union { f16 h[2]; unsigned u; } p;
    p.h[0] = (f16)v0; p.h[1] = (f16)v1;
    *(unsigned*)&tile[tl][c] = p.u;
  }
  __syncthreads();
  f16* xo = xh + ((size_t)b * T_DIM + t0) * C_DIM;
  int ch = tid & 15;
#pragma unroll
  for (int i = 0; i < 4; ++i) {
    int r = (tid >> 4) + i * 16;
    f16x8 v = *(const f16x8*)&tile[r][ch * 8];
    *(f16x8*)(xo + (size_t)r * C_DIM + ch * 8) = v;
  }
}

// ---------------- kernel 1: QKV projection GEMM ----------------
__global__ __launch_bounds__(256) void k_qkv(const f16* __restrict__ xh,
                                             const float* __restrict__ wqkv,
                                             const float* __restrict__ bqkv,
                                             f16* __restrict__ qh,
                                             f16* __restrict__ kh,
                                             f16* __restrict__ vt) {
  int tid = threadIdx.x;
  int w = tid >> 6, lane = tid & 63;
  int l15 = lane & 15, quad = lane >> 4;
  int o0 = blockIdx.x * 64 + w * 16;
  int t0 = blockIdx.y * 64;
  int b  = blockIdx.z;
  const f16* xb = xh + ((size_t)b * T_DIM + t0) * C_DIM;

  f32x4 acc[4] = {{0,0,0,0},{0,0,0,0},{0,0,0,0},{0,0,0,0}};
#pragma unroll
  for (int kc = 0; kc < 4; ++kc) {
    const float* wp = wqkv + (size_t)(o0 + l15) * C_DIM + kc * 32 + quad * 8;
    f16x8 af;
#pragma unroll
    for (int i = 0; i < 8; ++i) af[i] = (f16)wp[i];
#pragma unroll
    for (int nf = 0; nf < 4; ++nf) {
      f16x8 bf = *(const f16x8*)(xb + (size_t)(nf * 16 + l15) * C_DIM + kc * 32 + quad * 8);
      acc[nf] = __builtin_amdgcn_mfma_f32_16x16x32_f16(af, bf, acc[nf], 0, 0, 0);
    }
  }
  int ob   = o0 + quad * 4;
  int head = ob / 96;
  int r96  = ob % 96;
  int grp  = r96 >> 5;
  int c0   = r96 & 31;
  int bh   = b * NH + head;
  float bias[4];
#pragma unroll
  for (int r = 0; r < 4; ++r) bias[r] = bqkv[ob + r];
  const float SCALE2 = 0.17677669529663687f * 1.4426950408889634f;
#pragma unroll
  for (int nf = 0; nf < 4; ++nf) {
    int t = t0 + nf * 16 + l15;
    float v[4];
#pragma unroll
    for (int r = 0; r < 4; ++r) v[r] = acc[nf][r] + bias[r];
    if (grp == 0) {
      f16x4 q;
#pragma unroll
      for (int r = 0; r < 4; ++r) q[r] = (f16)(v[r] * SCALE2);
      *(f16x4*)(qh + ((size_t)bh * T_DIM + t) * CH + c0) = q;
    } else if (grp == 1) {
      f16x4 kk;
#pragma unroll
      for (int r = 0; r < 4; ++r) kk[r] = (f16)v[r];
      *(f16x4*)(kh + ((size_t)bh * T_DIM + t) * CH + c0) = kk;
    } else {
#pragma unroll
      for (int r = 0; r < 4; ++r)
        vt[((size_t)bh * CH + c0 + r) * T_DIM + t] = (f16)v[r];
    }
  }
}

// ---------------- kernel 2: flash attention, split-K over keys ----------------
// grid (32, 8, SPLITS), block 256 (4 waves x 32 q). S^T formulation:
//   S^T = mfma(A=K, B=Q): C col = q = lane&15 -> per-lane softmax state.
//   out^T = mfma(A=V^T, B=P^T): C col = q, row = c. l via ones-row A.
__global__ __launch_bounds__(256, 4) void k_attn(const f16* __restrict__ qh,
                                                 const f16* __restrict__ kh,
                                                 const f16* __restrict__ vt,
                                                 float* __restrict__ outp,
                                                 float* __restrict__ ml) {
  __shared__ f16 Ks[64][40];        // [s][c], pad 32->40
  __shared__ f16 Vs[32][72];        // [c][s], pad 64->72
  __shared__ f16 Ps[4][32][80];     // per-wave P^T->P round-trip, pad 64->80
  int tid = threadIdx.x;
  int w = tid >> 6, lane = tid & 63;
  int l15 = lane & 15, quad = lane >> 4;
  int bh    = blockIdx.y;
  int split = blockIdx.z;
  int q0    = blockIdx.x * 128 + w * 32;
  int s_base = split * S_SPLIT;

  // Q B-fragments: B[k=c=quad*8+j][n=q=l15]
  f16x8 qf[2];
#pragma unroll
  for (int nq = 0; nq < 2; ++nq)
    qf[nq] = *(const f16x8*)(qh + ((size_t)bh * T_DIM + q0 + nq * 16 + l15) * CH + quad * 8);

  f32x4 acc[2][2] = {{{0,0,0,0},{0,0,0,0}},{{0,0,0,0},{0,0,0,0}}}; // [csub][nq]
  f32x4 accl[2]   = {{0,0,0,0},{0,0,0,0}};   // l in row 0 (quad0,reg0)
  float mrow[2]   = {-1e30f, -1e30f};

  f16x8 onesA;   // A ones-row: m=0 -> l accumulation
#pragma unroll
  for (int i = 0; i < 8; ++i) onesA[i] = (l15 == 0) ? (f16)1.0f : (f16)0.0f;

  const f16* kbase = kh + ((size_t)bh * T_DIM + s_base + (tid >> 2)) * CH + (tid & 3) * 8;
  const f16* vbase = vt + ((size_t)bh * CH + (tid >> 3)) * T_DIM + s_base + (tid & 7) * 8;
  f16* ksdst = &Ks[tid >> 2][(tid & 3) * 8];
  f16* vsdst = &Vs[tid >> 3][(tid & 7) * 8];
  const f32x4 zf = {0, 0, 0, 0};

  for (int tile = 0; tile < NTILES; ++tile) {
    __syncthreads();
    *(uint4*)ksdst = *(const uint4*)kbase;
    *(uint4*)vsdst = *(const uint4*)vbase;
    kbase += 64 * CH;
    vbase += 64;
    __syncthreads();

    // K A-fragments (m=s), V^T A-fragments (m=c)
    f16x8 kf[4], vf[2][2];
#pragma unroll
    for (int nf = 0; nf < 4; ++nf)
      kf[nf] = *(const f16x8*)&Ks[nf * 16 + l15][quad * 8];
#pragma unroll
    for (int kc = 0; kc < 2; ++kc)
#pragma unroll
      for (int cs = 0; cs < 2; ++cs)
        vf[kc][cs] = *(const f16x8*)&Vs[cs * 16 + l15][kc * 32 + quad * 8];

#pragma unroll
    for (int nq = 0; nq < 2; ++nq) {
      f32x4 st[4];
#pragma unroll
      for (int nf = 0; nf < 4; ++nf)
        st[nf] = __builtin_amdgcn_mfma_f32_16x16x32_f16(kf[nf], qf[nq], zf, 0, 0, 0);
      // in-lane max over 16 s-values, then cross-quad (same q) reduce
      float mx = fmaxf(fmaxf(fmaxf(st[0][0], st[0][1]), fmaxf(st[0][2], st[0][3])),
                       fmaxf(fmaxf(st[1][0], st[1][1]), fmaxf(st[1][2], st[1][3])));
      float mx2 = fmaxf(fmaxf(fmaxf(st[2][0], st[2][1]), fmaxf(st[2][2], st[2][3])),
                        fmaxf(fmaxf(st[3][0], st[3][1]), fmaxf(st[3][2], st[3][3])));
      mx = fmaxf(mx, mx2);
      mx = fmaxf(mx, __shfl_xor(mx, 16));
      mx = fmaxf(mx, __shfl_xor(mx, 32));
      float mnew  = fmaxf(mrow[nq], mx);
      float alpha = exp2f(mrow[nq] - mnew);
      mrow[nq] = mnew;
#pragma unroll
      for (int cs = 0; cs < 2; ++cs)
#pragma unroll
        for (int r = 0; r < 4; ++r) acc[cs][nq][r] *= alpha;
      accl[nq][0] *= alpha;
#pragma unroll
      for (int nf = 0; nf < 4; ++nf) {
        f16x4 pk;
#pragma unroll
        for (int r = 0; r < 4; ++r) pk[r] = (f16)exp2f(st[nf][r] - mnew);
        *(f16x4*)&Ps[w][nq * 16 + l15][nf * 16 + quad * 4] = pk;  // 4 contig s
      }
    }

    // PV: out^T += V^T . P^T  (P^T read as B-fragment: 8 contig s per lane)
#pragma unroll
    for (int kc = 0; kc < 2; ++kc)
#pragma unroll
      for (int nq = 0; nq < 2; ++nq) {
        f16x8 pf = *(const f16x8*)&Ps[w][nq * 16 + l15][kc * 32 + quad * 8];
        acc[0][nq] = __builtin_amdgcn_mfma_f32_16x16x32_f16(vf[kc][0], pf, acc[0][nq], 0, 0, 0);
        acc[1][nq] = __builtin_amdgcn_mfma_f32_16x16x32_f16(vf[kc][1], pf, acc[1][nq], 0, 0, 0);
        accl[nq]   = __builtin_amdgcn_mfma_f32_16x16x32_f16(onesA,     pf, accl[nq],   0, 0, 0);
      }
  }

  // epilogue: write fp32 partials (out^T slabs + per-q m,l)
#pragma unroll
  for (int nq = 0; nq < 2; ++nq) {
    int q = q0 + nq * 16 + l15;
    size_t base = ((size_t)(bh * T_DIM + q) * SPLITS + split) * CH;
#pragma unroll
    for (int cs = 0; cs < 2; ++cs)
      *(f32x4*)(outp + base + cs * 16 + quad * 4) = acc[cs][nq];
    if (quad == 0) {
      size_t mb = ((size_t)(bh * T_DIM + q) * SPLITS + split) * 2;
      ml[mb]     = mrow[nq];
      ml[mb + 1] = accl[nq][0];
    }
  }
}

// ---------------- kernel 2b: combine split partials ----------------
__global__ __launch_bounds__(256) void k_combine(const float* __restrict__ outp,
                                                 const float* __restrict__ ml,
                                                 f16* __restrict__ ah) {
  int idx = blockIdx.x * 256 + threadIdx.x;   // NBH*T*CH = 1M threads
  int c  = idx & 31;
  int q  = (idx >> 5) & (T_DIM - 1);
  int bh = idx >> 17;
  size_t base = ((size_t)bh * T_DIM + q) * SPLITS;
  float m[SPLITS], l[SPLITS];
#pragma unroll
  for (int i = 0; i < SPLITS; ++i) {
    m[i] = ml[(base + i) * 2];
    l[i] = ml[(base + i) * 2 + 1];
  }
  float M = fmaxf(fmaxf(m[0], m[1]), fmaxf(m[2], m[3]));
  float L = 0.f, o = 0.f;
#pragma unroll
  for (int i = 0; i < SPLITS; ++i) {
    float wgt = exp2f(m[i] - M);
    L += l[i] * wgt;
    o += outp[(base + i) * CH + c] * wgt;
  }
  int b = bh >> 2, head = bh & 3;
  ah[((size_t)b * T_DIM + q) * C_DIM + head * CH + c] = (f16)(o / L);
}

// ---------------- kernel 3: output projection + residual ----------------
__global__ __launch_bounds__(256) void k_proj(const f16* __restrict__ ah,
                                              const float* __restrict__ wp,
                                              const float* __restrict__ bp,
                                              const float* __restrict__ x,
                                              float* __restrict__ out) {
  int tid = threadIdx.x;
  int w = tid >> 6, lane = tid & 63;
  int l15 = lane & 15, quad = lane >> 4;
  int o0 = blockIdx.x * 64 + w * 16;
  int t0 = blockIdx.y * 32;
  int b  = blockIdx.z;

  f32x4 acc[2] = {{0,0,0,0},{0,0,0,0}};
#pragma unroll
  for (int kc = 0; kc < 4; ++kc) {
    const float* wr = wp + (size_t)(o0 + l15) * C_DIM + kc * 32 + quad * 8;
    f16x8 af;
#pragma unroll
    for (int i = 0; i < 8; ++i) af[i] = (f16)wr[i];
#pragma unroll
    for (int nf = 0; nf < 2; ++nf) {
      f16x8 bf = *(const f16x8*)(ah + ((size_t)b * T_DIM + t0 + nf * 16 + l15) * C_DIM + kc * 32 + quad * 8);
      acc[nf] = __builtin_amdgcn_mfma_f32_16x16x32_f16(af, bf, acc[nf], 0, 0, 0);
    }
  }
  int ob = o0 + quad * 4;
  float bias[4];
#pragma unroll
  for (int r = 0; r < 4; ++r) bias[r] = bp[ob + r];
#pragma unroll
  for (int nf = 0; nf < 2; ++nf) {
#pragma unroll
    for (int r = 0; r < 4; ++r) {
      int t = t0 + nf * 16 + l15;
      size_t idx = ((size_t)b * C_DIM + ob + r) * T_DIM + t;
      out[idx] = x[idx] + bias[r] + acc[nf][r];
    }
  }
}

extern "C" void kernel_launch(void* const* d_in, const int* in_sizes, int n_in,
                              void* d_out, int out_size, void* d_ws, size_t ws_size,
                              hipStream_t stream) {
  const float* x     = (const float*)d_in[0];
  const float* wqkv  = (const float*)d_in[1];
  const float* bqkv  = (const float*)d_in[2];
  const float* wproj = (const float*)d_in[3];
  const float* bproj = (const float*)d_in[4];
  float* out = (float*)d_out;

  char* ws = (char*)d_ws;
  f16*   Xh   = (f16*)(ws);                      // 2MB (reused as Ah)
  f16*   Qh   = (f16*)(ws + (2u << 20));         // 2MB
  f16*   Kh   = (f16*)(ws + (4u << 20));         // 2MB
  f16*   Vt   = (f16*)(ws + (6u << 20));         // 2MB
  float* OutP = (float*)(ws + (8u << 20));       // SPLITS*8*4096*32*4 = 16MB
  float* ML   = (float*)(ws + (24u << 20));      // 1MB
  f16*   Ah   = Xh;

  k_transpose_x<<<dim3(64, 2), 256, 0, stream>>>(x, Xh);
  k_qkv<<<dim3(6, 64, 2), 256, 0, stream>>>(Xh, wqkv, bqkv, Qh, Kh, Vt);
  k_attn<<<dim3(32, NBH, SPLITS), 256, 0, stream>>>(Qh, Kh, Vt, OutP, ML);
  k_combine<<<dim3((NBH * T_DIM * CH) / 256), 256, 0, stream>>>(OutP, ML, Ah);
  k_proj<<<dim3(2, 128, 2), 256, 0, stream>>>(Ah, wproj, bproj, x, out);
}